// Round 15
// baseline (119.538 us; speedup 1.0000x reference)
//
#include <hip/hip_runtime.h>

// Trilinear warp (SpatialTransformer): vol [B=2,D=160,H=192,W=160,C=2] f32,
// flow [B,D,H,W,3] f32 ('ij'). Output f32, same shape as vol.
//
// R14 (65.3us): per-block stage -> vmcnt(0) drain -> compute; overlap only
// statistical (2 resident blocks). R15: persistent blocks (grid=256, 1/CU),
// 2-tile double-buffered LDS (147KB), counted vmcnt(1) + raw s_barrier:
// next tile's flow+stage DMA issued BEFORE computing current tile, so HBM/L2
// staging latency hides under compute (T3/T4/T14 pattern; never drain to 0
// in the loop). Consecutive tiles are w-adjacent -> halo stays L2-warm.

constexpr int Bb = 2, Dd = 160, Hh = 192, Ww = 160;
constexpr int HW  = Hh * Ww;          // 30720
constexpr int VOX = Dd * HW;          // 4,915,200 voxels per batch

constexpr int TD = 8,  TH = 16, TW = 16;   // output tile (2048 voxels)
constexpr int RD = TD + 8;                 // 16  staged region (halo 4)
constexpr int RH = TH + 8;                 // 24
constexpr int RW = TW + 8;                 // 24
constexpr int RWP = 24;                    // UNPADDED row stride (float2) — linear DMA
constexpr int QROW = RW / 2;               // 12 float4 quads per row
constexpr int NQ = RD * RH * QROW;         // 4608 staged quads (i*16B linear)
constexpr int BUF2 = NQ * 2;               // float2s per LDS buffer (9216)
constexpr int ND = Dd / TD, NH = Hh / TH, NW = Ww / TW;   // 20, 12, 10
constexpr int NTILE = Bb * ND * NH * NW;                  // 4800
constexpr int BLOCK = 1024;                // 16 waves
constexpr int GRID  = 256;                 // persistent, 1 block/CU
// 4800 = 192*19 + 64*18
constexpr size_t LDS_BYTES = (size_t)BUF2 * 2 * sizeof(float2);  // 147456 B

struct Ctx {
    int ox, oy, oz, ex, ey, ez, qz;   // staged region (block-uniform)
    int d, h, w, gidx;                // this thread's voxel-pair coords
    const float2* v2b;                // vol base for this tile's batch
};

__device__ __forceinline__ Ctx decode(int t, int tw2, int th, int td,
                                      const float2* __restrict__ v2base)
{
    Ctx c;
    const int bw = t % NW;  int r = t / NW;
    const int bh = r % NH;  r /= NH;
    const int bd = r % ND;  const int b = r / ND;
    const int d0 = bd * TD, h0 = bh * TH, w0 = bw * TW;
    c.ox = max(0, d0 - 4);  c.oy = max(0, h0 - 4);  c.oz = max(0, w0 - 4);
    c.ex = min(Dd - 1, d0 + TD + 3) - c.ox + 1;
    c.ey = min(Hh - 1, h0 + TH + 3) - c.oy + 1;
    c.ez = min(Ww - 1, w0 + TW + 3) - c.oz + 1;
    c.qz = c.ez >> 1;
    c.d = d0 + td;  c.h = h0 + th;  c.w = w0 + 2 * tw2;
    c.gidx = ((b * Dd + c.d) * Hh + c.h) * Ww + c.w;   // even
    c.v2b = v2base + (size_t)b * VOX;
    return c;
}

// stage one tile region into LDS via global_load_lds DMA (16B/lane, linear)
__device__ __forceinline__ void stage(const Ctx& c, float2* __restrict__ dst,
                                      int tid)
{
    if ((c.ex == RD) & (c.ey == RH) & (c.ez == RW)) {   // interior: clamp-free
        #pragma unroll 1
        for (int k = 0; k < 5; ++k) {
            const int i = tid + k * BLOCK;
            if (i < NQ) {                       // wave-uniform tail (512-aligned)
                const int lq = i % QROW;        // compile-time divisors
                const int t  = i / QROW;
                const int ly = t % RH;
                const int lx = t / RH;
                const float2* src = c.v2b +
                    ((size_t)(c.ox + lx) * HW + (c.oy + ly) * Ww + c.oz + 2 * lq);
                __builtin_amdgcn_global_load_lds(
                    (const __attribute__((address_space(1))) void*)src,
                    (__attribute__((address_space(3))) void*)(dst + (size_t)2 * i),
                    16, 0, 0);
            }
        }
    } else {
        #pragma unroll 1
        for (int k = 0; k < 5; ++k) {
            const int i = tid + k * BLOCK;
            if (i < NQ) {
                int lq = i % QROW;
                const int t  = i / QROW;
                int ly = t % RH;
                int lx = t / RH;
                lx = min(lx, c.ex - 1);  ly = min(ly, c.ey - 1);
                lq = min(lq, c.qz - 1);
                const float2* src = c.v2b +
                    ((size_t)(c.ox + lx) * HW + (c.oy + ly) * Ww + c.oz + 2 * lq);
                __builtin_amdgcn_global_load_lds(
                    (const __attribute__((address_space(1))) void*)src,
                    (__attribute__((address_space(3))) void*)(dst + (size_t)2 * i),
                    16, 0, 0);
            }
        }
    }
}

// Branchless LDS sample (R14-proven): flow-based ok, unclamped local coords,
// scalar dual-chain FMA. not-ok lanes read garbage; fixup overwrites.
__device__ __forceinline__ void sample_lds_f(const float2* __restrict__ buf,
                                             int ox, int oy, int oz,
                                             int dd, int hh, int ww,
                                             float fx, float fy, float fz,
                                             float& oxv, float& oyv, bool& ok)
{
    const float mn3 = fminf(fminf(fx, fy), fz);   // v_min3_f32
    const float mx3 = fmaxf(fmaxf(fx, fy), fz);   // v_max3_f32
    ok = (mn3 >= -4.0f) & (mx3 < 4.0f);

    const float lxf = (float)dd + fx;
    const float lyf = (float)hh + fy;
    const float lzf = (float)ww + fz;

    const int i0x = min(max(__float2int_rd(lxf), 0), Dd - 1);  // v_med3
    const int i0y = min(max(__float2int_rd(lyf), 0), Hh - 1);
    const int i0z = min(max(__float2int_rd(lzf), 0), Ww - 1);
    const int i1x = min(i0x + 1, Dd - 1);
    const int i1y = min(i0y + 1, Hh - 1);
    const int i1z = min(i0z + 1, Ww - 1);

    const float d1x = (float)i1x - lxf, d0x = 1.0f - d1x;
    const float d1y = (float)i1y - lyf, d0y = 1.0f - d1y;
    const float d1z = (float)i1z - lzf, d0z = 1.0f - d1z;

    const int a0x = i0x - ox, a1x = i1x - ox;
    const int a0y = i0y - oy, a1y = i1y - oy;
    const int a0z = i0z - oz, a1z = i1z - oz;

    const int r00 = (a0x * RH + a0y) * RWP;
    const int r01 = (a0x * RH + a1y) * RWP;
    const int r10 = (a1x * RH + a0y) * RWP;
    const int r11 = (a1x * RH + a1y) * RWP;
    const float2 c000 = buf[r00 + a0z], c001 = buf[r00 + a1z];
    const float2 c010 = buf[r01 + a0z], c011 = buf[r01 + a1z];
    const float2 c100 = buf[r10 + a0z], c101 = buf[r10 + a1z];
    const float2 c110 = buf[r11 + a0z], c111 = buf[r11 + a1z];

    const float xy00 = d1x * d1y, xy01 = d1x * d0y;
    const float xy10 = d0x * d1y, xy11 = d0x * d0y;
    const float w000 = xy00 * d1z, w001 = xy00 * d0z;
    const float w010 = xy01 * d1z, w011 = xy01 * d0z;
    const float w100 = xy10 * d1z, w101 = xy10 * d0z;
    const float w110 = xy11 * d1z, w111 = xy11 * d0z;

    oxv = w000 * c000.x;
    oyv = w000 * c000.y;
    oxv = fmaf(w001, c001.x, oxv);  oyv = fmaf(w001, c001.y, oyv);
    oxv = fmaf(w010, c010.x, oxv);  oyv = fmaf(w010, c010.y, oyv);
    oxv = fmaf(w011, c011.x, oxv);  oyv = fmaf(w011, c011.y, oyv);
    oxv = fmaf(w100, c100.x, oxv);  oyv = fmaf(w100, c100.y, oyv);
    oxv = fmaf(w101, c101.x, oxv);  oyv = fmaf(w101, c101.y, oyv);
    oxv = fmaf(w110, c110.x, oxv);  oyv = fmaf(w110, c110.y, oyv);
    oxv = fmaf(w111, c111.x, oxv);  oyv = fmaf(w111, c111.y, oyv);
}

// Exact reference math + global gathers — rare out-of-region lanes only.
__device__ __forceinline__ void sample_global(const float2* __restrict__ v2,
                                              int d, int h, int w,
                                              float fx, float fy, float fz,
                                              float& oxv, float& oyv)
{
    const float mx = (float)(Dd - 1), my = (float)(Hh - 1), mz = (float)(Ww - 1);
    const float lxf = (float)d + fx;
    const float lyf = (float)h + fy;
    const float lzf = (float)w + fz;

    const float l0x = fminf(fmaxf(floorf(lxf), 0.0f), mx);
    const float l0y = fminf(fmaxf(floorf(lyf), 0.0f), my);
    const float l0z = fminf(fmaxf(floorf(lzf), 0.0f), mz);
    const float l1x = fminf(l0x + 1.0f, mx);
    const float l1y = fminf(l0y + 1.0f, my);
    const float l1z = fminf(l0z + 1.0f, mz);

    const float d1x = l1x - lxf, d0x = 1.0f - d1x;
    const float d1y = l1y - lyf, d0y = 1.0f - d1y;
    const float d1z = l1z - lzf, d0z = 1.0f - d1z;

    const int i0x = (int)l0x, i1x = (int)l1x;
    const int i0y = (int)l0y, i1y = (int)l1y;
    const int i0z = (int)l0z, i1z = (int)l1z;

    const int rx0 = i0x * HW, rx1 = i1x * HW;
    const int ry0 = i0y * Ww, ry1 = i1y * Ww;
    const float2 c000 = v2[rx0 + ry0 + i0z], c001 = v2[rx0 + ry0 + i1z];
    const float2 c010 = v2[rx0 + ry1 + i0z], c011 = v2[rx0 + ry1 + i1z];
    const float2 c100 = v2[rx1 + ry0 + i0z], c101 = v2[rx1 + ry0 + i1z];
    const float2 c110 = v2[rx1 + ry1 + i0z], c111 = v2[rx1 + ry1 + i1z];

    const float w000 = d1x * d1y * d1z, w001 = d1x * d1y * d0z;
    const float w010 = d1x * d0y * d1z, w011 = d1x * d0y * d0z;
    const float w100 = d0x * d1y * d1z, w101 = d0x * d1y * d0z;
    const float w110 = d0x * d0y * d1z, w111 = d0x * d0y * d0z;

    oxv = w000 * c000.x;
    oyv = w000 * c000.y;
    oxv = fmaf(w001, c001.x, oxv);  oyv = fmaf(w001, c001.y, oyv);
    oxv = fmaf(w010, c010.x, oxv);  oyv = fmaf(w010, c010.y, oyv);
    oxv = fmaf(w011, c011.x, oxv);  oyv = fmaf(w011, c011.y, oyv);
    oxv = fmaf(w100, c100.x, oxv);  oyv = fmaf(w100, c100.y, oyv);
    oxv = fmaf(w101, c101.x, oxv);  oyv = fmaf(w101, c101.y, oyv);
    oxv = fmaf(w110, c110.x, oxv);  oyv = fmaf(w110, c110.y, oyv);
    oxv = fmaf(w111, c111.x, oxv);  oyv = fmaf(w111, c111.y, oyv);
}

__global__ __launch_bounds__(BLOCK, 4)   // 4 waves/EU (LDS-limited anyway) => VGPR<=128
void SpatialTransformer_44418551776013_kernel(const float* __restrict__ vol,
                                              const float* __restrict__ flow,
                                              float* __restrict__ out)
{
    extern __shared__ float2 sv[];   // two linear buffers of BUF2 float2s
    const int tid = threadIdx.x;
    const int tw2 = tid & 7;             // w-pair index 0..7
    const int th  = (tid >> 3) & 15;     // 0..15
    const int td  = tid >> 7;            // 0..7

    const float2* __restrict__ v2base = reinterpret_cast<const float2*>(vol);

    // persistent split: 4800 tiles over 256 blocks (192x19 + 64x18)
    const int bi    = blockIdx.x;
    const int tbase = bi * 18 + min(bi, 192);
    const int tcnt  = 18 + (bi < 192 ? 1 : 0);

    // ---- prologue: tile 0 flow + stage into buf0 ----
    Ctx ccur = decode(tbase, tw2, th, td, v2base);
    float4 fAc = *reinterpret_cast<const float4*>(flow + (size_t)ccur.gidx * 3);
    float2 fBc = *reinterpret_cast<const float2*>(flow + (size_t)ccur.gidx * 3 + 4);
    stage(ccur, sv, tid);

    Ctx ctxn = ccur;                 // next-tile state (named regs, rule #20)
    float4 fAn = fAc;  float2 fBn = fBc;

    #pragma unroll 1
    for (int k = 0; k < tcnt; ++k) {
        // wait own stage DMA for buf[k&1]. Steady state: stage(k) is older
        // than store(k-1) in the per-wave VMEM queue, so vmcnt(1) (allow the
        // newest 1 outstanding) forces it complete. k=0: nothing younger ->
        // drain fully.
        if (k == 0) { asm volatile("s_waitcnt vmcnt(0)" ::: "memory"); }
        else        { asm volatile("s_waitcnt vmcnt(1)" ::: "memory"); }
        __builtin_amdgcn_sched_barrier(0);
        __builtin_amdgcn_s_barrier();          // all waves: DMA landed, and
                                               // everyone done reading buf[(k+1)&1]
        asm volatile("" ::: "memory");         // no LDS reads float above
        __builtin_amdgcn_sched_barrier(0);

        // ---- issue next tile (flow loads + stage DMA) BEFORE compute ----
        if (k + 1 < tcnt) {
            ctxn = decode(tbase + k + 1, tw2, th, td, v2base);
            fAn = *reinterpret_cast<const float4*>(flow + (size_t)ctxn.gidx * 3);
            fBn = *reinterpret_cast<const float2*>(flow + (size_t)ctxn.gidx * 3 + 4);
            stage(ctxn, sv + (size_t)((k + 1) & 1) * BUF2, tid);
        }

        // ---- compute current tile from buf[k&1] ----
        const float2* __restrict__ buf = sv + (size_t)(k & 1) * BUF2;
        float o1x, o1y, o2x, o2y;
        bool ok1, ok2;
        sample_lds_f(buf, ccur.ox, ccur.oy, ccur.oz, ccur.d, ccur.h, ccur.w,
                     fAc.x, fAc.y, fAc.z, o1x, o1y, ok1);
        sample_lds_f(buf, ccur.ox, ccur.oy, ccur.oz, ccur.d, ccur.h, ccur.w + 1,
                     fAc.w, fBc.x, fBc.y, o2x, o2y, ok2);

        if (!__all(ok1 && ok2)) {   // deferred rare fixup (wave-uniform skip)
            if (!ok1) sample_global(ccur.v2b, ccur.d, ccur.h, ccur.w,
                                    fAc.x, fAc.y, fAc.z, o1x, o1y);
            if (!ok2) sample_global(ccur.v2b, ccur.d, ccur.h, ccur.w + 1,
                                    fAc.w, fBc.x, fBc.y, o2x, o2y);
        }

        *reinterpret_cast<float4*>(reinterpret_cast<float2*>(out) + ccur.gidx) =
            make_float4(o1x, o1y, o2x, o2y);

        // rotate next -> current (register renames, no spill)
        ccur = ctxn;  fAc = fAn;  fBc = fBn;
    }
}

extern "C" void kernel_launch(void* const* d_in, const int* in_sizes, int n_in,
                              void* d_out, int out_size, void* d_ws, size_t ws_size,
                              hipStream_t stream)
{
    const float* vol  = (const float*)d_in[0];   // [2,160,192,160,2] f32
    const float* flow = (const float*)d_in[1];   // [2,160,192,160,3] f32
    float* out = (float*)d_out;                  // [2,160,192,160,2] f32

    SpatialTransformer_44418551776013_kernel<<<GRID, BLOCK, LDS_BYTES, stream>>>(vol, flow, out);
}

// Round 16
// 64.439 us; speedup vs baseline: 1.8550x; 1.8550x over previous
//
#include <hip/hip_runtime.h>

// Trilinear warp (SpatialTransformer): vol [B=2,D=160,H=192,W=160,C=2] f32,
// flow [B,D,H,W,3] f32 ('ij'). Output f32, same shape as vol.
//
// R15 lesson: persistent 1-block/CU pipeline destroyed L2 locality
// (FETCH 132->355MB) + occupancy (77->43%): revert to R14 structure.
// R16 = R14 + phase-split: the ~120 VALU of coordinate/weight/address math
// per thread depends only on flow (not LDS), so compute it BEFORE the
// __syncthreads() vmcnt(0) drain — the wave fills its own stage-DMA wait.
// Flow loads are older than the 5 DMA loads -> compiler waits vmcnt(5) for
// them, DMAs stay in flight under the precompute.

constexpr int Bb = 2, Dd = 160, Hh = 192, Ww = 160;
constexpr int HW  = Hh * Ww;          // 30720
constexpr int VOX = Dd * HW;          // 4,915,200 voxels per batch

constexpr int TD = 8,  TH = 16, TW = 16;   // output tile (2048 voxels)
constexpr int RD = TD + 8;                 // 16  staged region (halo 4)
constexpr int RH = TH + 8;                 // 24
constexpr int RW = TW + 8;                 // 24
constexpr int RWP = 24;                    // UNPADDED row stride (float2) — linear DMA
constexpr int QROW = RW / 2;               // 12 float4 quads per row
constexpr int NQ = RD * RH * QROW;         // 4608 staged quads (i*16B linear)
constexpr int ND = Dd / TD, NH = Hh / TH, NW = Ww / TW;   // 20, 12, 10
constexpr int NBLK = Bb * ND * NH * NW;                   // 4800
constexpr int BLOCK = 1024;                // 16 waves; 2 voxels per thread
constexpr size_t LDS_BYTES = (size_t)NQ * 16;             // 73728 B

// Pre-barrier per-sample state: 8 LDS float2-indices + 8 weights + ok.
// Named scalar fields (rule #20: no runtime-indexed arrays).
struct PreS {
    int   p000, p001, p010, p011, p100, p101, p110, p111;
    float w000, w001, w010, w011, w100, w101, w110, w111;
    bool  ok;
};

// Coordinate/weight/address math — depends ONLY on flow + block constants.
// Identical numeric op order to R14 (med3 int path, xy*z weight products).
__device__ __forceinline__ PreS pre_sample(int ox, int oy, int oz,
                                           int dd, int hh, int ww,
                                           float fx, float fy, float fz)
{
    PreS s;
    const float mn3 = fminf(fminf(fx, fy), fz);   // v_min3_f32
    const float mx3 = fmaxf(fmaxf(fx, fy), fz);   // v_max3_f32
    s.ok = (mn3 >= -4.0f) & (mx3 < 4.0f);

    const float lxf = (float)dd + fx;
    const float lyf = (float)hh + fy;
    const float lzf = (float)ww + fz;

    const int i0x = min(max(__float2int_rd(lxf), 0), Dd - 1);  // v_med3
    const int i0y = min(max(__float2int_rd(lyf), 0), Hh - 1);
    const int i0z = min(max(__float2int_rd(lzf), 0), Ww - 1);
    const int i1x = min(i0x + 1, Dd - 1);
    const int i1y = min(i0y + 1, Hh - 1);
    const int i1z = min(i0z + 1, Ww - 1);

    const float d1x = (float)i1x - lxf, d0x = 1.0f - d1x;
    const float d1y = (float)i1y - lyf, d0y = 1.0f - d1y;
    const float d1z = (float)i1z - lzf, d0z = 1.0f - d1z;

    // region-local coords, UNCLAMPED (ok lanes in-bounds by the flow test;
    // not-ok lanes may go OOB in LDS: HW returns 0, fixup overwrites)
    const int a0x = i0x - ox, a1x = i1x - ox;
    const int a0y = i0y - oy, a1y = i1y - oy;
    const int a0z = i0z - oz, a1z = i1z - oz;

    const int r00 = (a0x * RH + a0y) * RWP;
    const int r01 = (a0x * RH + a1y) * RWP;
    const int r10 = (a1x * RH + a0y) * RWP;
    const int r11 = (a1x * RH + a1y) * RWP;
    s.p000 = r00 + a0z;  s.p001 = r00 + a1z;
    s.p010 = r01 + a0z;  s.p011 = r01 + a1z;
    s.p100 = r10 + a0z;  s.p101 = r10 + a1z;
    s.p110 = r11 + a0z;  s.p111 = r11 + a1z;

    const float xy00 = d1x * d1y, xy01 = d1x * d0y;
    const float xy10 = d0x * d1y, xy11 = d0x * d0y;
    s.w000 = xy00 * d1z;  s.w001 = xy00 * d0z;
    s.w010 = xy01 * d1z;  s.w011 = xy01 * d0z;
    s.w100 = xy10 * d1z;  s.w101 = xy10 * d0z;
    s.w110 = xy11 * d1z;  s.w111 = xy11 * d0z;
    return s;
}

// Exact reference math + global gathers — rare out-of-region lanes only.
__device__ __forceinline__ void sample_global(const float2* __restrict__ v2,
                                              int d, int h, int w,
                                              float fx, float fy, float fz,
                                              float& oxv, float& oyv)
{
    const float mx = (float)(Dd - 1), my = (float)(Hh - 1), mz = (float)(Ww - 1);
    const float lxf = (float)d + fx;
    const float lyf = (float)h + fy;
    const float lzf = (float)w + fz;

    const float l0x = fminf(fmaxf(floorf(lxf), 0.0f), mx);
    const float l0y = fminf(fmaxf(floorf(lyf), 0.0f), my);
    const float l0z = fminf(fmaxf(floorf(lzf), 0.0f), mz);
    const float l1x = fminf(l0x + 1.0f, mx);
    const float l1y = fminf(l0y + 1.0f, my);
    const float l1z = fminf(l0z + 1.0f, mz);

    const float d1x = l1x - lxf, d0x = 1.0f - d1x;
    const float d1y = l1y - lyf, d0y = 1.0f - d1y;
    const float d1z = l1z - lzf, d0z = 1.0f - d1z;

    const int i0x = (int)l0x, i1x = (int)l1x;
    const int i0y = (int)l0y, i1y = (int)l1y;
    const int i0z = (int)l0z, i1z = (int)l1z;

    const int rx0 = i0x * HW, rx1 = i1x * HW;
    const int ry0 = i0y * Ww, ry1 = i1y * Ww;
    const float2 c000 = v2[rx0 + ry0 + i0z], c001 = v2[rx0 + ry0 + i1z];
    const float2 c010 = v2[rx0 + ry1 + i0z], c011 = v2[rx0 + ry1 + i1z];
    const float2 c100 = v2[rx1 + ry0 + i0z], c101 = v2[rx1 + ry0 + i1z];
    const float2 c110 = v2[rx1 + ry1 + i0z], c111 = v2[rx1 + ry1 + i1z];

    const float w000 = d1x * d1y * d1z, w001 = d1x * d1y * d0z;
    const float w010 = d1x * d0y * d1z, w011 = d1x * d0y * d0z;
    const float w100 = d0x * d1y * d1z, w101 = d0x * d1y * d0z;
    const float w110 = d0x * d0y * d1z, w111 = d0x * d0y * d0z;

    oxv = w000 * c000.x;
    oyv = w000 * c000.y;
    oxv = fmaf(w001, c001.x, oxv);  oyv = fmaf(w001, c001.y, oyv);
    oxv = fmaf(w010, c010.x, oxv);  oyv = fmaf(w010, c010.y, oyv);
    oxv = fmaf(w011, c011.x, oxv);  oyv = fmaf(w011, c011.y, oyv);
    oxv = fmaf(w100, c100.x, oxv);  oyv = fmaf(w100, c100.y, oyv);
    oxv = fmaf(w101, c101.x, oxv);  oyv = fmaf(w101, c101.y, oyv);
    oxv = fmaf(w110, c110.x, oxv);  oyv = fmaf(w110, c110.y, oyv);
    oxv = fmaf(w111, c111.x, oxv);  oyv = fmaf(w111, c111.y, oyv);
}

__global__ __launch_bounds__(BLOCK, 8)   // 8 waves/EU => VGPR<=64 => 2 blocks/CU
void SpatialTransformer_44418551776013_kernel(const float* __restrict__ vol,
                                              const float* __restrict__ flow,
                                              float* __restrict__ out)
{
    extern __shared__ float2 sv[];   // [RD][RH][RWP], linear
    const int tid = threadIdx.x;

    // bijective XCD swizzle (NBLK % 8 == 0). Validated: FETCH 222 -> 132 MB.
    constexpr int CPX = NBLK / 8;    // 600
    int bid = (int)(blockIdx.x % 8) * CPX + (int)(blockIdx.x / 8);

    const int bw = bid % NW;  bid /= NW;
    const int bh = bid % NH;  bid /= NH;
    const int bd = bid % ND;
    const int b  = bid / ND;
    const int d0 = bd * TD, h0 = bh * TH, w0 = bw * TW;

    // staged region = clip(tile +- 4); block-uniform -> SGPRs
    const int ox = max(0, d0 - 4), oy = max(0, h0 - 4), oz = max(0, w0 - 4);
    const int ex = min(Dd - 1, d0 + TD + 3) - ox + 1;   // <= RD
    const int ey = min(Hh - 1, h0 + TH + 3) - oy + 1;   // <= RH
    const int ez = min(Ww - 1, w0 + TW + 3) - oz + 1;   // <= RW, even
    const int qz = ez >> 1;

    // compute mapping: (td, th, tw2); thread owns voxels (d,h,w) & (d,h,w+1)
    const int tw2 = tid & 7;             // w-pair index 0..7
    const int th  = (tid >> 3) & 15;     // 0..15
    const int td  = tid >> 7;            // 0..7
    const int h = h0 + th;
    const int w = w0 + 2 * tw2;
    const int d = d0 + td;
    const int gidx = ((b * Dd + d) * Hh + h) * Ww + w;   // even

    // flow for BOTH voxels = 6 contiguous floats (issued FIRST — oldest in
    // the vmcnt queue, so consuming them waits only vmcnt(5): DMAs in flight)
    const float4 fA = *reinterpret_cast<const float4*>(flow + (size_t)gidx * 3);
    const float2 fB = *reinterpret_cast<const float2*>(flow + (size_t)gidx * 3 + 4);
    // voxel 1: (fA.x, fA.y, fA.z)   voxel 2: (fA.w, fB.x, fB.y)

    const float2* __restrict__ v2 =
        reinterpret_cast<const float2*>(vol) + (size_t)b * VOX;

    // ---- stage region via global_load_lds DMA (16B/lane, linear dest) ----
    if ((ex == RD) & (ey == RH) & (ez == RW)) {   // interior: clamp-free
        #pragma unroll 1
        for (int k = 0; k < 5; ++k) {
            const int i = tid + k * BLOCK;
            if (i < NQ) {                        // wave-uniform tail (512-aligned)
                const int lq = i % QROW;         // compile-time divisors
                const int t  = i / QROW;
                const int ly = t % RH;
                const int lx = t / RH;
                const float2* src =
                    v2 + ((size_t)(ox + lx) * HW + (oy + ly) * Ww + oz + 2 * lq);
                __builtin_amdgcn_global_load_lds(
                    (const __attribute__((address_space(1))) void*)src,
                    (__attribute__((address_space(3))) void*)(sv + (size_t)2 * i),
                    16, 0, 0);
            }
        }
    } else {
        #pragma unroll 1
        for (int k = 0; k < 5; ++k) {
            const int i = tid + k * BLOCK;
            if (i < NQ) {
                int lq = i % QROW;
                const int t  = i / QROW;
                int ly = t % RH;
                int lx = t / RH;
                lx = min(lx, ex - 1);  ly = min(ly, ey - 1);  lq = min(lq, qz - 1);
                const float2* src =
                    v2 + ((size_t)(ox + lx) * HW + (oy + ly) * Ww + oz + 2 * lq);
                __builtin_amdgcn_global_load_lds(
                    (const __attribute__((address_space(1))) void*)src,
                    (__attribute__((address_space(3))) void*)(sv + (size_t)2 * i),
                    16, 0, 0);
            }
        }
    }

    // ---- PRE-BARRIER: coordinate/weight/address math (no LDS dependency).
    // Fills this wave's own stage-DMA drain wait. ~120 VALU/thread.
    const PreS s1 = pre_sample(ox, oy, oz, d, h, w,     fA.x, fA.y, fA.z);
    const PreS s2 = pre_sample(ox, oy, oz, d, h, w + 1, fA.w, fB.x, fB.y);

    __builtin_amdgcn_sched_barrier(0);   // pin precompute above the drain
    __syncthreads();                     // vmcnt(0) drain + s_barrier

    // ---- POST-BARRIER: 16 ds_reads + dual-chain FMA only ----
    const float2 a000 = sv[s1.p000], a001 = sv[s1.p001];
    const float2 a010 = sv[s1.p010], a011 = sv[s1.p011];
    const float2 a100 = sv[s1.p100], a101 = sv[s1.p101];
    const float2 a110 = sv[s1.p110], a111 = sv[s1.p111];
    const float2 b000 = sv[s2.p000], b001 = sv[s2.p001];
    const float2 b010 = sv[s2.p010], b011 = sv[s2.p011];
    const float2 b100 = sv[s2.p100], b101 = sv[s2.p101];
    const float2 b110 = sv[s2.p110], b111 = sv[s2.p111];

    float o1x = s1.w000 * a000.x;
    float o1y = s1.w000 * a000.y;
    o1x = fmaf(s1.w001, a001.x, o1x);  o1y = fmaf(s1.w001, a001.y, o1y);
    o1x = fmaf(s1.w010, a010.x, o1x);  o1y = fmaf(s1.w010, a010.y, o1y);
    o1x = fmaf(s1.w011, a011.x, o1x);  o1y = fmaf(s1.w011, a011.y, o1y);
    o1x = fmaf(s1.w100, a100.x, o1x);  o1y = fmaf(s1.w100, a100.y, o1y);
    o1x = fmaf(s1.w101, a101.x, o1x);  o1y = fmaf(s1.w101, a101.y, o1y);
    o1x = fmaf(s1.w110, a110.x, o1x);  o1y = fmaf(s1.w110, a110.y, o1y);
    o1x = fmaf(s1.w111, a111.x, o1x);  o1y = fmaf(s1.w111, a111.y, o1y);

    float o2x = s2.w000 * b000.x;
    float o2y = s2.w000 * b000.y;
    o2x = fmaf(s2.w001, b001.x, o2x);  o2y = fmaf(s2.w001, b001.y, o2y);
    o2x = fmaf(s2.w010, b010.x, o2x);  o2y = fmaf(s2.w010, b010.y, o2y);
    o2x = fmaf(s2.w011, b011.x, o2x);  o2y = fmaf(s2.w011, b011.y, o2y);
    o2x = fmaf(s2.w100, b100.x, o2x);  o2y = fmaf(s2.w100, b100.y, o2y);
    o2x = fmaf(s2.w101, b101.x, o2x);  o2y = fmaf(s2.w101, b101.y, o2y);
    o2x = fmaf(s2.w110, b110.x, o2x);  o2y = fmaf(s2.w110, b110.y, o2y);
    o2x = fmaf(s2.w111, b111.x, o2x);  o2y = fmaf(s2.w111, b111.y, o2y);

    // ---- deferred rare fixup (wave-uniform skip for ~all waves) ----
    if (!__all(s1.ok && s2.ok)) {
        if (!s1.ok) sample_global(v2, d, h, w,     fA.x, fA.y, fA.z, o1x, o1y);
        if (!s2.ok) sample_global(v2, d, h, w + 1, fA.w, fB.x, fB.y, o2x, o2y);
    }

    // both voxels' outputs are adjacent float2s -> one 16B-aligned store
    *reinterpret_cast<float4*>(reinterpret_cast<float2*>(out) + gidx) =
        make_float4(o1x, o1y, o2x, o2y);
}

extern "C" void kernel_launch(void* const* d_in, const int* in_sizes, int n_in,
                              void* d_out, int out_size, void* d_ws, size_t ws_size,
                              hipStream_t stream)
{
    const float* vol  = (const float*)d_in[0];   // [2,160,192,160,2] f32
    const float* flow = (const float*)d_in[1];   // [2,160,192,160,3] f32
    float* out = (float*)d_out;                  // [2,160,192,160,2] f32

    SpatialTransformer_44418551776013_kernel<<<NBLK, BLOCK, LDS_BYTES, stream>>>(vol, flow, out);
}